// Round 4
// baseline (285.717 us; speedup 1.0000x reference)
//
#include <hip/hip_runtime.h>

// B=1024, H=512, E=512, V=50257, L=2 bidirectional GRU (1 step) + vocab projection + softmax.
// bf16 MFMA GEMMs (256x128 tile, 8 waves, double-buffered LDS, f32-B fused convert), f32 accum.
// Softmax via bf16 exp-stash + flat-index scale pass.

#define Bsz 1024
#define Hs  512
#define Vv  50257
#define VP  50304          // V padded to multiple of 128 (393*128)
#define NG  1536           // 3*H
#define NPB 393            // VP/128

typedef __bf16 bf16x8 __attribute__((ext_vector_type(8)));
typedef float  floatx4 __attribute__((ext_vector_type(4)));

__device__ __forceinline__ unsigned short f2bf(float f) {
  unsigned int u = __builtin_bit_cast(unsigned int, f);
  u += 0x7fffu + ((u >> 16) & 1u);          // RNE
  return (unsigned short)(u >> 16);
}

__device__ __forceinline__ float bf2f(unsigned short u) {
  unsigned int x = (unsigned int)u << 16;
  return __builtin_bit_cast(float, x);
}

__device__ __forceinline__ void cvt4(const float* src, unsigned short* dst) {
  float4 f = *(const float4*)src;
  unsigned int lo = (unsigned int)f2bf(f.x) | ((unsigned int)f2bf(f.y) << 16);
  unsigned int hi = (unsigned int)f2bf(f.z) | ((unsigned int)f2bf(f.w) << 16);
  *(uint2*)dst = make_uint2(lo, hi);
}

// async global->LDS, 16B per lane. LDS dest is wave-uniform base + lane*16.
__device__ __forceinline__ void g2lds16(const void* g, void* l) {
  unsigned long long gv = (unsigned long long)g;
  unsigned int lv = (unsigned int)(unsigned long long)l;
  __builtin_amdgcn_global_load_lds(
      (const __attribute__((address_space(1))) unsigned int*)gv,
      (__attribute__((address_space(3))) unsigned int*)lv,
      16, 0, 0);
}

// ---------------- GEMM staging helpers ---------------------------------------------------------
// A tile 256x64 bf16 (32KB): 32 chunks of 1KB, wave w stages chunks 4w..4w+3 via global_load_lds.
// LDS layout: byte t16*16 where t16=row*8+c holds source col-slot sc = c ^ (row&7)  (XOR swizzle).
__device__ __forceinline__ void stage_issueA(const unsigned short* A, int K, int mt, int kt,
                                             unsigned short* Abuf, int w, int l) {
#pragma unroll
  for (int i = 0; i < 4; ++i) {
    int chunk = w * 4 + i;
    int t16 = chunk * 64 + l;
    int row = t16 >> 3, c = t16 & 7;
    int sc = c ^ (row & 7);
    g2lds16(A + (size_t)(mt * 256 + row) * K + kt * 64 + sc * 8, (char*)Abuf + chunk * 1024);
  }
}

// B tile 128x64 bf16 (16KB) staged from an f32 source (fused convert): global->reg here.
__device__ __forceinline__ void stage_loadB(const float* Bw, int K, int nt, int kt, int maxrow,
                                            float4 (&regs)[2][2], int w, int l) {
#pragma unroll
  for (int i = 0; i < 2; ++i) {
    int chunk = w * 2 + i;
    int t16 = chunk * 64 + l;
    int row = t16 >> 3, c = t16 & 7;
    int sc = c ^ (row & 7);
    int rg = nt * 128 + row;
    if (rg > maxrow) rg = maxrow;            // pad rows: clamp (cols masked by bias=-1e30)
    const float* src = Bw + (size_t)rg * K + kt * 64 + sc * 8;
    regs[i][0] = *(const float4*)src;
    regs[i][1] = *(const float4*)(src + 4);
  }
}

__device__ __forceinline__ void stage_writeB(const float4 (&regs)[2][2], unsigned short* Bbuf,
                                             int w, int l) {
#pragma unroll
  for (int i = 0; i < 2; ++i) {
    int chunk = w * 2 + i;
    uint4 p;
    p.x = (unsigned int)f2bf(regs[i][0].x) | ((unsigned int)f2bf(regs[i][0].y) << 16);
    p.y = (unsigned int)f2bf(regs[i][0].z) | ((unsigned int)f2bf(regs[i][0].w) << 16);
    p.z = (unsigned int)f2bf(regs[i][1].x) | ((unsigned int)f2bf(regs[i][1].y) << 16);
    p.w = (unsigned int)f2bf(regs[i][1].z) | ((unsigned int)f2bf(regs[i][1].w) << 16);
    *(uint4*)((char*)Bbuf + chunk * 1024 + l * 16) = p;
  }
}

__device__ __forceinline__ void compute_step(const unsigned short* Acur, const unsigned short* Bcur,
                                             floatx4 (&acc)[4][4], int wr, int wc, int g, int r16) {
#pragma unroll
  for (int ks = 0; ks < 2; ++ks) {
    bf16x8 a[4], b[4];
#pragma unroll
    for (int i = 0; i < 4; ++i) {
      int rowA = wr * 64 + i * 16 + r16;
      int ca = (ks * 4 + g) ^ (rowA & 7);
      a[i] = *(const bf16x8*)((const char*)Acur + rowA * 128 + ca * 16);
      int rowB = wc * 64 + i * 16 + r16;
      int cb = (ks * 4 + g) ^ (rowB & 7);
      b[i] = *(const bf16x8*)((const char*)Bcur + rowB * 128 + cb * 16);
    }
#pragma unroll
    for (int i = 0; i < 4; ++i)
#pragma unroll
      for (int j = 0; j < 4; ++j)
        acc[i][j] = __builtin_amdgcn_mfma_f32_16x16x32_bf16(a[i], b[j], acc[i][j], 0, 0, 0);
  }
}

// ---------------- GEMM core: C(256x128 tile) = A(bf16) * B(f32->bf16)^T, double-buffered -------
// 512 threads = 8 waves; each wave 64x64 via 4x4 frags of 16x16x32 MFMA.
// Prefetch tile k+1 (A via global_load_lds, B via reg) before computing tile k; B cvt+ds_write
// lands after the MFMAs (issue-early / write-late), one barrier per K-step.
__device__ __forceinline__ void gemm_core_db(const unsigned short* A, const float* Bw, int K,
                                             int mt, int nt, int maxrowB,
                                             unsigned short (&Alds)[2][16384],
                                             unsigned short (&Blds)[2][8192],
                                             floatx4 (&acc)[4][4]) {
  const int tid = threadIdx.x;
  const int w = tid >> 6, l = tid & 63;
  const int wr = w >> 1, wc = w & 1;
  const int g = l >> 4, r16 = l & 15;
  floatx4 zero = {0.f, 0.f, 0.f, 0.f};
#pragma unroll
  for (int i = 0; i < 4; ++i)
#pragma unroll
    for (int j = 0; j < 4; ++j) acc[i][j] = zero;

  const int nsteps = K >> 6;     // BK = 64
  float4 regs[2][2];
  // prologue: tile 0
  stage_issueA(A, K, mt, 0, Alds[0], w, l);
  stage_loadB(Bw, K, nt, 0, maxrowB, regs, w, l);
  stage_writeB(regs, Blds[0], w, l);
  __syncthreads();               // drains vmcnt+lgkmcnt: tile 0 resident
  int cur = 0;
  for (int kt = 0; kt < nsteps; ++kt) {
    const bool pf = (kt + 1 < nsteps);
    if (pf) {
      stage_issueA(A, K, mt, kt + 1, Alds[cur ^ 1], w, l);
      stage_loadB(Bw, K, nt, kt + 1, maxrowB, regs, w, l);
    }
    compute_step(Alds[cur], Blds[cur], acc, wr, wc, g, r16);   // overlaps in-flight loads
    if (pf) stage_writeB(regs, Blds[cur ^ 1], w, l);           // waits only on B regs
    __syncthreads();             // next tile resident; readers of old buffer done
    cur ^= 1;
  }
}

// ---------------- batched GRU gate GEMMs (z = 0..3: {gi d0, gi d1, gh d0, gh d1}) -------------
struct GemmDesc {
  const unsigned short* A[4];
  const float* Bw[4];            // f32 weights, converted on the fly
  const float* bias[4];
  float* C[4];
  int K[4];
};

__global__ __launch_bounds__(512, 2) void gemm_gru_batch(GemmDesc d) {
  __shared__ alignas(16) unsigned short Alds[2][16384];
  __shared__ alignas(16) unsigned short Blds[2][8192];
  const int z = blockIdx.z;
  floatx4 acc[4][4];
  gemm_core_db(d.A[z], d.Bw[z], d.K[z], blockIdx.y, blockIdx.x, NG - 1, Alds, Blds, acc);
  const float* bias = d.bias[z];
  float* C = d.C[z];
  const int tid = threadIdx.x, w = tid >> 6, l = tid & 63;
  const int wr = w >> 1, wc = w & 1, g = l >> 4, r16 = l & 15;
#pragma unroll
  for (int i = 0; i < 4; ++i)
#pragma unroll
    for (int j = 0; j < 4; ++j) {
      int col = blockIdx.x * 128 + wc * 64 + j * 16 + r16;
      float bc = bias[col];
#pragma unroll
      for (int q = 0; q < 4; ++q) {
        int row = blockIdx.y * 256 + wr * 64 + i * 16 + g * 4 + q;
        C[(size_t)row * NG + col] = acc[i][j][q] + bc;
      }
    }
}

// ---------------- projection GEMM ---------------------------------------------------------------
// MODE 0: exp -> bf16 stash + row partial sums.  MODE 1: partial sums only.
// MODE 2: exp * inv[row] -> f32 probs (recompute fallback).
template <int MODE>
__global__ __launch_bounds__(512, 2) void gemm_proj(const unsigned short* A, const float* Bw,
                                                    const float* biasp, unsigned short* stash,
                                                    float* probs, float* partial, const float* inv) {
  __shared__ alignas(16) unsigned short Alds[2][16384];
  __shared__ alignas(16) unsigned short Blds[2][8192];
  __shared__ float rowpart[256];
  const int tid = threadIdx.x;
  if (MODE != 2 && tid < 256) rowpart[tid] = 0.f;
  // bijective XCD-chunk swizzle: nwg=1572, q=196, r=4
  int orig = blockIdx.x;
  int xcd = orig & 7, slot = orig >> 3;
  int wgid = (xcd < 4 ? xcd * 197 : 788 + (xcd - 4) * 196) + slot;
  int mt = wgid & 3, nt = wgid >> 2;     // consecutive wgid share nt -> B-panel L2 reuse
  floatx4 acc[4][4];
  gemm_core_db(A, Bw, 512, mt, nt, Vv - 1, Alds, Blds, acc);
  const int w = tid >> 6, l = tid & 63;
  const int wr = w >> 1, wc = w & 1, g = l >> 4, r16 = l & 15;
  float bcol[4];
#pragma unroll
  for (int j = 0; j < 4; ++j) bcol[j] = biasp[nt * 128 + wc * 64 + j * 16 + r16];
#pragma unroll
  for (int i = 0; i < 4; ++i)
#pragma unroll
    for (int q = 0; q < 4; ++q) {
      int rowl = wr * 64 + i * 16 + g * 4 + q;
      int grow = mt * 256 + rowl;
      float rinv = (MODE == 2) ? inv[grow] : 0.f;
      float s = 0.f;
#pragma unroll
      for (int j = 0; j < 4; ++j) {
        int col = nt * 128 + wc * 64 + j * 16 + r16;
        float v = __expf(acc[i][j][q] + bcol[j]);     // pad cols: bias=-1e30 -> v=0
        if (MODE == 0) stash[(size_t)grow * VP + col] = f2bf(v);
        if (MODE == 2) { if (col < Vv) probs[(size_t)grow * Vv + col] = v * rinv; }
        s += v;
      }
      if (MODE != 2) {
        s += __shfl_xor(s, 1); s += __shfl_xor(s, 2);
        s += __shfl_xor(s, 4); s += __shfl_xor(s, 8);
        if (r16 == 0) atomicAdd(&rowpart[rowl], s);   // 2 commutative adds per row: deterministic
      }
    }
  if (MODE != 2) {
    __syncthreads();
    if (tid < 256) partial[(size_t)(mt * 256 + tid) * NPB + nt] = rowpart[tid];
  }
}

// ---------------- elementwise GRU gates ---------------------------------------------------------
__global__ __launch_bounds__(256) void gru_gates(const float* Cbuf, const float* hidden,
                                                 float* out_newh, unsigned short* bf_out, int layer) {
  int idx = blockIdx.x * 256 + threadIdx.x;    // 2^20 total
  int j = idx & 511;
  int b = (idx >> 9) & 1023;
  int d = idx >> 19;
  const float* GI = Cbuf + (size_t)d * Bsz * NG;
  const float* GH = Cbuf + (size_t)(2 + d) * Bsz * NG;
  size_t base = (size_t)b * NG + j;
  float ir = GI[base], iz = GI[base + 512], inn = GI[base + 1024];
  float hr = GH[base], hz = GH[base + 512], hn = GH[base + 1024];
  float r = 1.f / (1.f + __expf(-(ir + hr)));
  float z = 1.f / (1.f + __expf(-(iz + hz)));
  float n = tanhf(inn + r * hn);
  size_t hoff = (size_t)(2 * layer + d) * (Bsz * Hs) + (size_t)b * Hs + j;
  float hprev = hidden[hoff];
  float h = (1.f - z) * n + z * hprev;
  out_newh[hoff] = h;
  if (layer == 0) {
    bf_out[(size_t)b * 1024 + d * 512 + j] = f2bf(h);     // inp1 = concat(hf, hb)
  } else if (d == 1) {
    bf_out[(size_t)b * 512 + j] = f2bf(h);                // hb1 feeds projection
  }
}

// ---------------- small conversions (hidden -> bf16, bproj pad) ---------------------------------
__global__ void convert_small(const float* hidden, const float* bproj,
                              unsigned short* hbf, float* bprojp) {
  long long idx = ((long long)blockIdx.x * 256 + threadIdx.x) * 4;
  if (idx < 2097152) { cvt4(hidden + idx, hbf + idx); return; }
  idx -= 2097152;
  if (idx < VP) {
    float4 v;
    v.x = (idx + 0 < Vv) ? bproj[idx + 0] : -1e30f;
    v.y = (idx + 1 < Vv) ? bproj[idx + 1] : -1e30f;
    v.z = (idx + 2 < Vv) ? bproj[idx + 2] : -1e30f;
    v.w = (idx + 3 < Vv) ? bproj[idx + 3] : -1e30f;
    *(float4*)(bprojp + idx) = v;
  }
}

__global__ void gather_embed(const int* x, const float* embed, unsigned short* xe) {
  int b = blockIdx.x, t = threadIdx.x;
  int tok = x[b];
  float2 v = *(const float2*)(embed + (size_t)tok * 512 + t * 2);
  unsigned int o = ((unsigned int)f2bf(v.y) << 16) | f2bf(v.x);
  *(unsigned int*)((unsigned short*)xe + (size_t)b * 512 + t * 2) = o;
}

// ---------------- softmax normalization --------------------------------------------------------
__global__ void rowsum_inv(const float* partial, float* inv) {
  int row = blockIdx.x, tid = threadIdx.x;   // 128 threads
  float s = 0.f;
  for (int c = tid; c < NPB; c += 128) s += partial[(size_t)row * NPB + c];
  __shared__ float tmp[128];
  tmp[tid] = s;
  __syncthreads();
  for (int off = 64; off > 0; off >>= 1) {
    if (tid < off) tmp[tid] += tmp[tid + off];
    __syncthreads();
  }
  if (tid == 0) inv[row] = 1.0f / tmp[0];
}

// Flat-index normalize+expand: thread f owns probs[4f..4f+4) -> aligned float4 store, no tail.
__global__ __launch_bounds__(256) void scale_expand(const unsigned short* stash, const float* inv,
                                                    float* probs) {
  const unsigned int nquad = 12865792u;        // (1024*50257)/4 exactly
  const unsigned int step = gridDim.x * 256u;
  for (unsigned int f = blockIdx.x * 256u + threadIdx.x; f < nquad; f += step) {
    unsigned int e0 = f * 4u;                  // flat element index, < 2^26
    unsigned int row = e0 / (unsigned int)Vv;  // magic-multiply division
    int col = (int)(e0 - row * (unsigned int)Vv);
    float4 o;
    if (col + 4 <= Vv) {                       // single-row fast path
      float s = inv[row];
      const unsigned short* sp = stash + (size_t)row * VP + col;
      if ((col & 1) == 0) {                    // 4B-aligned: two uint loads (row-uniform branch)
        unsigned int u0 = *(const unsigned int*)sp;
        unsigned int u1 = *(const unsigned int*)(sp + 2);
        o.x = bf2f((unsigned short)u0) * s;
        o.y = bf2f((unsigned short)(u0 >> 16)) * s;
        o.z = bf2f((unsigned short)u1) * s;
        o.w = bf2f((unsigned short)(u1 >> 16)) * s;
      } else {
        o.x = bf2f(sp[0]) * s; o.y = bf2f(sp[1]) * s;
        o.z = bf2f(sp[2]) * s; o.w = bf2f(sp[3]) * s;
      }
    } else {                                   // row-straddling thread (1023 total)
      float vals[4];
#pragma unroll
      for (int k = 0; k < 4; ++k) {
        unsigned int e = e0 + k;
        unsigned int rk = e / (unsigned int)Vv;
        int ck = (int)(e - rk * (unsigned int)Vv);
        vals[k] = bf2f(stash[(size_t)rk * VP + ck]) * inv[rk];
      }
      o.x = vals[0]; o.y = vals[1]; o.z = vals[2]; o.w = vals[3];
    }
    *(float4*)(probs + e0) = o;                // always 16B-aligned, fully coalesced
  }
}

// ---------------- host-side launch -------------------------------------------------------------
extern "C" void kernel_launch(void* const* d_in, const int* in_sizes, int n_in,
                              void* d_out, int out_size, void* d_ws, size_t ws_size,
                              hipStream_t stream) {
  const int*   x      = (const int*)d_in[0];
  const float* hidden = (const float*)d_in[1];
  const float* embed  = (const float*)d_in[2];
  const float* Wih0   = (const float*)d_in[3];
  const float* Whh0   = (const float*)d_in[4];
  const float* bih0   = (const float*)d_in[5];
  const float* bhh0   = (const float*)d_in[6];
  const float* Wih1   = (const float*)d_in[7];
  const float* Whh1   = (const float*)d_in[8];
  const float* bih1   = (const float*)d_in[9];
  const float* bhh1   = (const float*)d_in[10];
  const float* Wproj  = (const float*)d_in[11];
  const float* bproj  = (const float*)d_in[12];
  float* out = (float*)d_out;

  char* ws = (char*)d_ws;
  unsigned short* hbf    = (unsigned short*)(ws);              //  4,194,304 B
  float*          bprojp = (float*)(ws + 4194304);             //    201,216 B
  unsigned short* xe     = (unsigned short*)(ws + 4395520);    //  1,048,576 B
  unsigned short* inp1   = (unsigned short*)(ws + 5444096);    //  2,097,152 B
  unsigned short* hb1    = (unsigned short*)(ws + 7541248);    //  1,048,576 B
  float*          Cbuf   = (float*)(ws + 8589824);             // 25,165,824 B
  float*          partial= (float*)(ws + 33755648);            //  1,609,728 B
  float*          inv    = (float*)(ws + 35365376);            //      4,096 B
  unsigned short* stash  = (unsigned short*)(ws + 35369472);   // 103,022,592 B
  const size_t NEED_STASH = 35369472ull + (size_t)Bsz * VP * 2ull;   // ~138.4 MB

  float* out_newh = out + 51463168ll;   // 1024*50257

  convert_small<<<2098, 256, 0, stream>>>(hidden, bproj, hbf, bprojp);
  gather_embed<<<1024, 256, 0, stream>>>(x, embed, xe);

  // layer 0
  GemmDesc d0;
  d0.A[0] = xe;  d0.A[1] = xe;
  d0.A[2] = hbf; d0.A[3] = hbf + 524288;
  d0.Bw[0] = Wih0; d0.Bw[1] = Wih0 + 786432;
  d0.Bw[2] = Whh0; d0.Bw[3] = Whh0 + 786432;
  d0.bias[0] = bih0; d0.bias[1] = bih0 + 1536;
  d0.bias[2] = bhh0; d0.bias[3] = bhh0 + 1536;
  d0.C[0] = Cbuf;             d0.C[1] = Cbuf + 1572864;
  d0.C[2] = Cbuf + 2*1572864; d0.C[3] = Cbuf + 3*1572864;
  d0.K[0] = d0.K[1] = d0.K[2] = d0.K[3] = 512;
  gemm_gru_batch<<<dim3(12, 4, 4), 512, 0, stream>>>(d0);
  gru_gates<<<4096, 256, 0, stream>>>(Cbuf, hidden, out_newh, inp1, 0);

  // layer 1
  GemmDesc d1;
  d1.A[0] = inp1; d1.A[1] = inp1;
  d1.A[2] = hbf + 2*524288; d1.A[3] = hbf + 3*524288;
  d1.Bw[0] = Wih1; d1.Bw[1] = Wih1 + 1572864;
  d1.Bw[2] = Whh1; d1.Bw[3] = Whh1 + 786432;
  d1.bias[0] = bih1; d1.bias[1] = bih1 + 1536;
  d1.bias[2] = bhh1; d1.bias[3] = bhh1 + 1536;
  d1.C[0] = Cbuf;             d1.C[1] = Cbuf + 1572864;
  d1.C[2] = Cbuf + 2*1572864; d1.C[3] = Cbuf + 3*1572864;
  d1.K[0] = d1.K[1] = 1024; d1.K[2] = d1.K[3] = 512;
  gemm_gru_batch<<<dim3(12, 4, 4), 512, 0, stream>>>(d1);
  gru_gates<<<4096, 256, 0, stream>>>(Cbuf, hidden, out_newh, hb1, 1);

  // projection + softmax
  if (ws_size >= NEED_STASH) {
    gemm_proj<0><<<1572, 512, 0, stream>>>(hb1, Wproj, bprojp, stash, out, partial, inv);
    rowsum_inv<<<1024, 128, 0, stream>>>(partial, inv);
    scale_expand<<<8192, 256, 0, stream>>>(stash, inv, out);
  } else {
    gemm_proj<1><<<1572, 512, 0, stream>>>(hb1, Wproj, bprojp, stash, out, partial, inv);
    rowsum_inv<<<1024, 128, 0, stream>>>(partial, inv);
    gemm_proj<2><<<1572, 512, 0, stream>>>(hb1, Wproj, bprojp, stash, out, partial, inv);
  }
}

// Round 5
// 252.444 us; speedup vs baseline: 1.1318x; 1.1318x over previous
//
#include <hip/hip_runtime.h>

// B=1024, H=512, E=512, V=50257, L=2 bidirectional GRU (1 step) + vocab projection + softmax.
// bf16 MFMA GEMMs (256x128 tile, 8 waves, single-buffered 2-barrier core), f32 accum.
// gemm_proj fuses the Wproj f32->bf16 convert into B staging (reg->cvt->ds_write).
// Softmax via bf16 exp-stash + flat-index scale pass.

#define Bsz 1024
#define Hs  512
#define Vv  50257
#define VP  50304          // V padded to multiple of 128 (393*128)
#define NG  1536           // 3*H
#define NPB 393            // VP/128

typedef __bf16 bf16x8 __attribute__((ext_vector_type(8)));
typedef float  floatx4 __attribute__((ext_vector_type(4)));

__device__ __forceinline__ unsigned short f2bf(float f) {
  unsigned int u = __builtin_bit_cast(unsigned int, f);
  u += 0x7fffu + ((u >> 16) & 1u);          // RNE
  return (unsigned short)(u >> 16);
}

__device__ __forceinline__ float bf2f(unsigned short u) {
  unsigned int x = (unsigned int)u << 16;
  return __builtin_bit_cast(float, x);
}

__device__ __forceinline__ void cvt4(const float* src, unsigned short* dst) {
  float4 f = *(const float4*)src;
  unsigned int lo = (unsigned int)f2bf(f.x) | ((unsigned int)f2bf(f.y) << 16);
  unsigned int hi = (unsigned int)f2bf(f.z) | ((unsigned int)f2bf(f.w) << 16);
  *(uint2*)dst = make_uint2(lo, hi);
}

// async global->LDS, 16B per lane. LDS dest is wave-uniform base + lane*16.
__device__ __forceinline__ void g2lds16(const void* g, void* l) {
  unsigned long long gv = (unsigned long long)g;
  unsigned int lv = (unsigned int)(unsigned long long)l;
  __builtin_amdgcn_global_load_lds(
      (const __attribute__((address_space(1))) unsigned int*)gv,
      (__attribute__((address_space(3))) unsigned int*)lv,
      16, 0, 0);
}

// ---------------- shared MFMA compute step ------------------------------------------------------
__device__ __forceinline__ void compute_step(const unsigned short* Acur, const unsigned short* Bcur,
                                             floatx4 (&acc)[4][4], int wr, int wc, int g, int r16) {
#pragma unroll
  for (int ks = 0; ks < 2; ++ks) {
    bf16x8 a[4], b[4];
#pragma unroll
    for (int i = 0; i < 4; ++i) {
      int rowA = wr * 64 + i * 16 + r16;
      int ca = (ks * 4 + g) ^ (rowA & 7);
      a[i] = *(const bf16x8*)((const char*)Acur + rowA * 128 + ca * 16);
      int rowB = wc * 64 + i * 16 + r16;
      int cb = (ks * 4 + g) ^ (rowB & 7);
      b[i] = *(const bf16x8*)((const char*)Bcur + rowB * 128 + cb * 16);
    }
#pragma unroll
    for (int i = 0; i < 4; ++i)
#pragma unroll
      for (int j = 0; j < 4; ++j)
        acc[i][j] = __builtin_amdgcn_mfma_f32_16x16x32_bf16(a[i], b[j], acc[i][j], 0, 0, 0);
  }
}

// ---------------- GEMM core (bf16 A and B via global_load_lds), single-buffered ----------------
// 512 threads = 8 waves; each wave 64x64 via 4x4 frags of 16x16x32 MFMA.
// LDS: A 256x64 (32KB), B 128x64 (16KB), XOR-swizzled via pre-swizzled global source.
__device__ __forceinline__ void gemm_core8(const unsigned short* A, const unsigned short* Bw, int K,
                                           int mt, int nt,
                                           unsigned short* Alds, unsigned short* Blds,
                                           floatx4 (&acc)[4][4]) {
  const int tid = threadIdx.x;
  const int w = tid >> 6, l = tid & 63;
  const int wr = w >> 1, wc = w & 1;
  const int g = l >> 4, r16 = l & 15;
  floatx4 zero = {0.f, 0.f, 0.f, 0.f};
#pragma unroll
  for (int i = 0; i < 4; ++i)
#pragma unroll
    for (int j = 0; j < 4; ++j) acc[i][j] = zero;

  const int nsteps = K >> 6;     // BK = 64
  for (int kt = 0; kt < nsteps; ++kt) {
    __syncthreads();             // protect LDS from previous iteration's readers
#pragma unroll
    for (int i = 0; i < 4; ++i) {            // A: 32 chunks of 1KB
      int chunk = w * 4 + i;
      int t16 = chunk * 64 + l;
      int row = t16 >> 3, c = t16 & 7;
      int sc = c ^ (row & 7);
      g2lds16(A + (size_t)(mt * 256 + row) * K + kt * 64 + sc * 8, (char*)Alds + chunk * 1024);
    }
#pragma unroll
    for (int i = 0; i < 2; ++i) {            // B: 16 chunks of 1KB
      int chunk = w * 2 + i;
      int t16 = chunk * 64 + l;
      int row = t16 >> 3, c = t16 & 7;
      int sc = c ^ (row & 7);
      g2lds16(Bw + (size_t)(nt * 128 + row) * K + kt * 64 + sc * 8, (char*)Blds + chunk * 1024);
    }
    __syncthreads();             // drains vmcnt(0) before s_barrier
    compute_step(Alds, Blds, acc, wr, wc, g, r16);
  }
}

// ---------------- GEMM core with fused f32->bf16 B staging (single-buffered) -------------------
__device__ __forceinline__ void gemm_coreBf32(const unsigned short* A, const float* Bw, int K,
                                              int mt, int nt, int maxrowB,
                                              unsigned short* Alds, unsigned short* Blds,
                                              floatx4 (&acc)[4][4]) {
  const int tid = threadIdx.x;
  const int w = tid >> 6, l = tid & 63;
  const int wr = w >> 1, wc = w & 1;
  const int g = l >> 4, r16 = l & 15;
  floatx4 zero = {0.f, 0.f, 0.f, 0.f};
#pragma unroll
  for (int i = 0; i < 4; ++i)
#pragma unroll
    for (int j = 0; j < 4; ++j) acc[i][j] = zero;

  // per-thread B chunk geometry (2 chunks of 1KB)
  int brow[2], bsc[2];
#pragma unroll
  for (int i = 0; i < 2; ++i) {
    int chunk = w * 2 + i;
    int t16 = chunk * 64 + l;
    brow[i] = t16 >> 3;
    bsc[i] = (t16 & 7) ^ (brow[i] & 7);
  }
  int brg[2];
#pragma unroll
  for (int i = 0; i < 2; ++i) {
    int rg = nt * 128 + brow[i];
    brg[i] = (rg > maxrowB) ? maxrowB : rg;   // pad rows clamp (cols masked by bias=-1e30)
  }

  const int nsteps = K >> 6;     // BK = 64
  for (int kt = 0; kt < nsteps; ++kt) {
    __syncthreads();             // previous iteration's readers done
    // B: f32 global -> regs (issued first so cvt's wait doesn't cover A's loads)
    float4 rb[2][2];
#pragma unroll
    for (int i = 0; i < 2; ++i) {
      const float* src = Bw + (size_t)brg[i] * K + kt * 64 + bsc[i] * 8;
      rb[i][0] = *(const float4*)src;
      rb[i][1] = *(const float4*)(src + 4);
    }
    // A: async global->LDS
#pragma unroll
    for (int i = 0; i < 4; ++i) {
      int chunk = w * 4 + i;
      int t16 = chunk * 64 + l;
      int row = t16 >> 3, c = t16 & 7;
      int sc = c ^ (row & 7);
      g2lds16(A + (size_t)(mt * 256 + row) * K + kt * 64 + sc * 8, (char*)Alds + chunk * 1024);
    }
    // B: cvt + ds_write_b128 into same swizzled layout
#pragma unroll
    for (int i = 0; i < 2; ++i) {
      uint4 p;
      p.x = (unsigned int)f2bf(rb[i][0].x) | ((unsigned int)f2bf(rb[i][0].y) << 16);
      p.y = (unsigned int)f2bf(rb[i][0].z) | ((unsigned int)f2bf(rb[i][0].w) << 16);
      p.z = (unsigned int)f2bf(rb[i][1].x) | ((unsigned int)f2bf(rb[i][1].y) << 16);
      p.w = (unsigned int)f2bf(rb[i][1].z) | ((unsigned int)f2bf(rb[i][1].w) << 16);
      *(uint4*)((char*)Blds + (w * 2 + i) * 1024 + l * 16) = p;
    }
    __syncthreads();             // drains vmcnt (A) + lgkm (B writes)
    compute_step(Alds, Blds, acc, wr, wc, g, r16);
  }
}

// ---------------- batched GRU gate GEMMs (z = 0..3: {gi d0, gi d1, gh d0, gh d1}) -------------
struct GemmDesc {
  const unsigned short* A[4];
  const unsigned short* Bw[4];
  const float* bias[4];
  float* C[4];
  int K[4];
};

__global__ __launch_bounds__(512, 4) void gemm_gru_batch(GemmDesc d) {
  __shared__ alignas(16) unsigned short Alds[256 * 64];
  __shared__ alignas(16) unsigned short Blds[128 * 64];
  const int z = blockIdx.z;
  floatx4 acc[4][4];
  gemm_core8(d.A[z], d.Bw[z], d.K[z], blockIdx.y, blockIdx.x, Alds, Blds, acc);
  const float* bias = d.bias[z];
  float* C = d.C[z];
  const int tid = threadIdx.x, w = tid >> 6, l = tid & 63;
  const int wr = w >> 1, wc = w & 1, g = l >> 4, r16 = l & 15;
#pragma unroll
  for (int i = 0; i < 4; ++i)
#pragma unroll
    for (int j = 0; j < 4; ++j) {
      int col = blockIdx.x * 128 + wc * 64 + j * 16 + r16;
      float bc = bias[col];
#pragma unroll
      for (int q = 0; q < 4; ++q) {
        int row = blockIdx.y * 256 + wr * 64 + i * 16 + g * 4 + q;
        C[(size_t)row * NG + col] = acc[i][j][q] + bc;
      }
    }
}

// ---------------- projection GEMM (f32 B fused convert) -----------------------------------------
// MODE 0: exp -> bf16 stash + row partial sums.  MODE 1: partial sums only.
// MODE 2: exp * inv[row] -> f32 probs (recompute fallback).
template <int MODE>
__global__ __launch_bounds__(512, 4) void gemm_proj(const unsigned short* A, const float* Bw,
                                                    const float* biasp, unsigned short* stash,
                                                    float* probs, float* partial, const float* inv) {
  __shared__ alignas(16) unsigned short Alds[256 * 64];
  __shared__ alignas(16) unsigned short Blds[128 * 64];
  __shared__ float rowpart[256];
  const int tid = threadIdx.x;
  if (MODE != 2 && tid < 256) rowpart[tid] = 0.f;
  // bijective XCD-chunk swizzle: nwg=1572, q=196, r=4
  int orig = blockIdx.x;
  int xcd = orig & 7, slot = orig >> 3;
  int wgid = (xcd < 4 ? xcd * 197 : 788 + (xcd - 4) * 196) + slot;
  int mt = wgid & 3, nt = wgid >> 2;     // consecutive wgid share nt -> B-panel L2 reuse
  floatx4 acc[4][4];
  gemm_coreBf32(A, Bw, 512, mt, nt, Vv - 1, Alds, Blds, acc);
  const int w = tid >> 6, l = tid & 63;
  const int wr = w >> 1, wc = w & 1, g = l >> 4, r16 = l & 15;
  float bcol[4];
#pragma unroll
  for (int j = 0; j < 4; ++j) bcol[j] = biasp[nt * 128 + wc * 64 + j * 16 + r16];
#pragma unroll
  for (int i = 0; i < 4; ++i)
#pragma unroll
    for (int q = 0; q < 4; ++q) {
      int rowl = wr * 64 + i * 16 + g * 4 + q;
      int grow = mt * 256 + rowl;
      float rinv = (MODE == 2) ? inv[grow] : 0.f;
      float s = 0.f;
#pragma unroll
      for (int j = 0; j < 4; ++j) {
        int col = nt * 128 + wc * 64 + j * 16 + r16;
        float v = __expf(acc[i][j][q] + bcol[j]);     // pad cols: bias=-1e30 -> v=0
        if (MODE == 0) stash[(size_t)grow * VP + col] = f2bf(v);
        if (MODE == 2) { if (col < Vv) probs[(size_t)grow * Vv + col] = v * rinv; }
        s += v;
      }
      if (MODE != 2) {
        s += __shfl_xor(s, 1); s += __shfl_xor(s, 2);
        s += __shfl_xor(s, 4); s += __shfl_xor(s, 8);
        if (r16 == 0) atomicAdd(&rowpart[rowl], s);   // 2 commutative adds per row: deterministic
      }
    }
  if (MODE != 2) {
    __syncthreads();
    if (tid < 256) partial[(size_t)(mt * 256 + tid) * NPB + nt] = rowpart[tid];
  }
}

// ---------------- elementwise GRU gates ---------------------------------------------------------
__global__ __launch_bounds__(256) void gru_gates(const float* Cbuf, const float* hidden,
                                                 float* out_newh, unsigned short* bf_out, int layer) {
  int idx = blockIdx.x * 256 + threadIdx.x;    // 2^20 total
  int j = idx & 511;
  int b = (idx >> 9) & 1023;
  int d = idx >> 19;
  const float* GI = Cbuf + (size_t)d * Bsz * NG;
  const float* GH = Cbuf + (size_t)(2 + d) * Bsz * NG;
  size_t base = (size_t)b * NG + j;
  float ir = GI[base], iz = GI[base + 512], inn = GI[base + 1024];
  float hr = GH[base], hz = GH[base + 512], hn = GH[base + 1024];
  float r = 1.f / (1.f + __expf(-(ir + hr)));
  float z = 1.f / (1.f + __expf(-(iz + hz)));
  float n = tanhf(inn + r * hn);
  size_t hoff = (size_t)(2 * layer + d) * (Bsz * Hs) + (size_t)b * Hs + j;
  float hprev = hidden[hoff];
  float h = (1.f - z) * n + z * hprev;
  out_newh[hoff] = h;
  if (layer == 0) {
    bf_out[(size_t)b * 1024 + d * 512 + j] = f2bf(h);     // inp1 = concat(hf, hb)
  } else if (d == 1) {
    bf_out[(size_t)b * 512 + j] = f2bf(h);                // hb1 feeds projection
  }
}

// ---------------- conversions: GRU weights + hidden + bproj pad (vectorized x4) ----------------
__global__ void convert_small(const float* Wih0, const float* Whh0, const float* Wih1,
                              const float* Whh1, const float* hidden, const float* bproj,
                              unsigned short* wih0b, unsigned short* whh0b, unsigned short* wih1b,
                              unsigned short* whh1b, unsigned short* hbf, float* bprojp) {
  long long idx = ((long long)blockIdx.x * 256 + threadIdx.x) * 4;
  if (idx < 1572864) { cvt4(Wih0 + idx, wih0b + idx); return; }
  idx -= 1572864;
  if (idx < 1572864) { cvt4(Whh0 + idx, whh0b + idx); return; }
  idx -= 1572864;
  if (idx < 3145728) { cvt4(Wih1 + idx, wih1b + idx); return; }
  idx -= 3145728;
  if (idx < 1572864) { cvt4(Whh1 + idx, whh1b + idx); return; }
  idx -= 1572864;
  if (idx < 2097152) { cvt4(hidden + idx, hbf + idx); return; }
  idx -= 2097152;
  if (idx < VP) {
    float4 v;
    v.x = (idx + 0 < Vv) ? bproj[idx + 0] : -1e30f;
    v.y = (idx + 1 < Vv) ? bproj[idx + 1] : -1e30f;
    v.z = (idx + 2 < Vv) ? bproj[idx + 2] : -1e30f;
    v.w = (idx + 3 < Vv) ? bproj[idx + 3] : -1e30f;
    *(float4*)(bprojp + idx) = v;
  }
}

__global__ void gather_embed(const int* x, const float* embed, unsigned short* xe) {
  int b = blockIdx.x, t = threadIdx.x;
  int tok = x[b];
  float2 v = *(const float2*)(embed + (size_t)tok * 512 + t * 2);
  unsigned int o = ((unsigned int)f2bf(v.y) << 16) | f2bf(v.x);
  *(unsigned int*)((unsigned short*)xe + (size_t)b * 512 + t * 2) = o;
}

// ---------------- softmax normalization --------------------------------------------------------
__global__ void rowsum_inv(const float* partial, float* inv) {
  int row = blockIdx.x, tid = threadIdx.x;   // 128 threads
  float s = 0.f;
  for (int c = tid; c < NPB; c += 128) s += partial[(size_t)row * NPB + c];
  __shared__ float tmp[128];
  tmp[tid] = s;
  __syncthreads();
  for (int off = 64; off > 0; off >>= 1) {
    if (tid < off) tmp[tid] += tmp[tid + off];
    __syncthreads();
  }
  if (tid == 0) inv[row] = 1.0f / tmp[0];
}

// Flat-index normalize+expand: thread f owns probs[4f..4f+4) -> aligned float4 store, no tail.
__global__ __launch_bounds__(256) void scale_expand(const unsigned short* stash, const float* inv,
                                                    float* probs) {
  const unsigned int nquad = 12865792u;        // (1024*50257)/4 exactly
  const unsigned int step = gridDim.x * 256u;
  for (unsigned int f = blockIdx.x * 256u + threadIdx.x; f < nquad; f += step) {
    unsigned int e0 = f * 4u;                  // flat element index, < 2^26
    unsigned int row = e0 / (unsigned int)Vv;  // magic-multiply division
    int col = (int)(e0 - row * (unsigned int)Vv);
    float4 o;
    if (col + 4 <= Vv) {                       // single-row fast path
      float s = inv[row];
      const unsigned short* sp = stash + (size_t)row * VP + col;
      if ((col & 1) == 0) {                    // 4B-aligned: two uint loads (row-uniform branch)
        unsigned int u0 = *(const unsigned int*)sp;
        unsigned int u1 = *(const unsigned int*)(sp + 2);
        o.x = bf2f((unsigned short)u0) * s;
        o.y = bf2f((unsigned short)(u0 >> 16)) * s;
        o.z = bf2f((unsigned short)u1) * s;
        o.w = bf2f((unsigned short)(u1 >> 16)) * s;
      } else {
        o.x = bf2f(sp[0]) * s; o.y = bf2f(sp[1]) * s;
        o.z = bf2f(sp[2]) * s; o.w = bf2f(sp[3]) * s;
      }
    } else {                                   // row-straddling thread (1023 total)
      float vals[4];
#pragma unroll
      for (int k = 0; k < 4; ++k) {
        unsigned int e = e0 + k;
        unsigned int rk = e / (unsigned int)Vv;
        int ck = (int)(e - rk * (unsigned int)Vv);
        vals[k] = bf2f(stash[(size_t)rk * VP + ck]) * inv[rk];
      }
      o.x = vals[0]; o.y = vals[1]; o.z = vals[2]; o.w = vals[3];
    }
    *(float4*)(probs + e0) = o;                // always 16B-aligned, fully coalesced
  }
}

// ---------------- host-side launch -------------------------------------------------------------
extern "C" void kernel_launch(void* const* d_in, const int* in_sizes, int n_in,
                              void* d_out, int out_size, void* d_ws, size_t ws_size,
                              hipStream_t stream) {
  const int*   x      = (const int*)d_in[0];
  const float* hidden = (const float*)d_in[1];
  const float* embed  = (const float*)d_in[2];
  const float* Wih0   = (const float*)d_in[3];
  const float* Whh0   = (const float*)d_in[4];
  const float* bih0   = (const float*)d_in[5];
  const float* bhh0   = (const float*)d_in[6];
  const float* Wih1   = (const float*)d_in[7];
  const float* Whh1   = (const float*)d_in[8];
  const float* bih1   = (const float*)d_in[9];
  const float* bhh1   = (const float*)d_in[10];
  const float* Wproj  = (const float*)d_in[11];
  const float* bproj  = (const float*)d_in[12];
  float* out = (float*)d_out;

  char* ws = (char*)d_ws;
  unsigned short* wih0b  = (unsigned short*)(ws);              //  3,145,728 B
  unsigned short* whh0b  = (unsigned short*)(ws + 3145728);    //  3,145,728 B
  unsigned short* wih1b  = (unsigned short*)(ws + 6291456);    //  6,291,456 B
  unsigned short* whh1b  = (unsigned short*)(ws + 12582912);   //  3,145,728 B
  unsigned short* hbf    = (unsigned short*)(ws + 15728640);   //  4,194,304 B
  float*          bprojp = (float*)(ws + 19922944);            //    201,216 B
  unsigned short* xe     = (unsigned short*)(ws + 20124160);   //  1,048,576 B
  unsigned short* inp1   = (unsigned short*)(ws + 21172736);   //  2,097,152 B
  unsigned short* hb1    = (unsigned short*)(ws + 23269888);   //  1,048,576 B
  float*          Cbuf   = (float*)(ws + 24318464);            // 25,165,824 B
  float*          partial= (float*)(ws + 49484288);            //  1,609,728 B
  float*          inv    = (float*)(ws + 51094016);            //      4,096 B
  unsigned short* stash  = (unsigned short*)(ws + 51098112);   // 103,022,592 B
  const size_t NEED_STASH = 51098112ull + (size_t)Bsz * VP * 2ull;   // ~154 MB

  float* out_newh = out + 51463168ll;   // 1024*50257

  convert_small<<<9778, 256, 0, stream>>>(Wih0, Whh0, Wih1, Whh1, hidden, bproj,
                                          wih0b, whh0b, wih1b, whh1b, hbf, bprojp);
  gather_embed<<<1024, 256, 0, stream>>>(x, embed, xe);

  // layer 0
  GemmDesc d0;
  d0.A[0] = xe;  d0.A[1] = xe;
  d0.A[2] = hbf; d0.A[3] = hbf + 524288;
  d0.Bw[0] = wih0b; d0.Bw[1] = wih0b + 786432;
  d0.Bw[2] = whh0b; d0.Bw[3] = whh0b + 786432;
  d0.bias[0] = bih0; d0.bias[1] = bih0 + 1536;
  d0.bias[2] = bhh0; d0.bias[3] = bhh0 + 1536;
  d0.C[0] = Cbuf;             d0.C[1] = Cbuf + 1572864;
  d0.C[2] = Cbuf + 2*1572864; d0.C[3] = Cbuf + 3*1572864;
  d0.K[0] = d0.K[1] = d0.K[2] = d0.K[3] = 512;
  gemm_gru_batch<<<dim3(12, 4, 4), 512, 0, stream>>>(d0);
  gru_gates<<<4096, 256, 0, stream>>>(Cbuf, hidden, out_newh, inp1, 0);

  // layer 1
  GemmDesc d1;
  d1.A[0] = inp1; d1.A[1] = inp1;
  d1.A[2] = hbf + 2*524288; d1.A[3] = hbf + 3*524288;
  d1.Bw[0] = wih1b; d1.Bw[1] = wih1b + 1572864;
  d1.Bw[2] = whh1b; d1.Bw[3] = whh1b + 786432;
  d1.bias[0] = bih1; d1.bias[1] = bih1 + 1536;
  d1.bias[2] = bhh1; d1.bias[3] = bhh1 + 1536;
  d1.C[0] = Cbuf;             d1.C[1] = Cbuf + 1572864;
  d1.C[2] = Cbuf + 2*1572864; d1.C[3] = Cbuf + 3*1572864;
  d1.K[0] = d1.K[1] = 1024; d1.K[2] = d1.K[3] = 512;
  gemm_gru_batch<<<dim3(12, 4, 4), 512, 0, stream>>>(d1);
  gru_gates<<<4096, 256, 0, stream>>>(Cbuf, hidden, out_newh, hb1, 1);

  // projection + softmax
  if (ws_size >= NEED_STASH) {
    gemm_proj<0><<<1572, 512, 0, stream>>>(hb1, Wproj, bprojp, stash, out, partial, inv);
    rowsum_inv<<<1024, 128, 0, stream>>>(partial, inv);
    scale_expand<<<8192, 256, 0, stream>>>(stash, inv, out);
  } else {
    gemm_proj<1><<<1572, 512, 0, stream>>>(hb1, Wproj, bprojp, stash, out, partial, inv);
    rowsum_inv<<<1024, 128, 0, stream>>>(partial, inv);
    gemm_proj<2><<<1572, 512, 0, stream>>>(hb1, Wproj, bprojp, stash, out, partial, inv);
  }
}

// Round 6
// 251.130 us; speedup vs baseline: 1.1377x; 1.0052x over previous
//
#include <hip/hip_runtime.h>

// B=1024, H=512, E=512, V=50257, L=2 bidirectional GRU (1 step) + vocab projection + softmax.
// GRU GEMMs: proven 256x128 2-barrier core. Projection: 256x256 8-phase counted-vmcnt kernel.
// Softmax via bf16 exp-stash + flat-index scale pass.

#define Bsz 1024
#define Hs  512
#define Vv  50257
#define VP2 50432          // V padded to multiple of 256 (197*256)
#define NG  1536           // 3*H
#define NPB2 197           // VP2/256
#define NPBF 393           // fallback: 50304/128

typedef __bf16 bf16x8 __attribute__((ext_vector_type(8)));
typedef float  floatx4 __attribute__((ext_vector_type(4)));

__device__ __forceinline__ unsigned short f2bf(float f) {
  unsigned int u = __builtin_bit_cast(unsigned int, f);
  u += 0x7fffu + ((u >> 16) & 1u);          // RNE
  return (unsigned short)(u >> 16);
}

__device__ __forceinline__ float bf2f(unsigned short u) {
  unsigned int x = (unsigned int)u << 16;
  return __builtin_bit_cast(float, x);
}

__device__ __forceinline__ void cvt4(const float* src, unsigned short* dst) {
  float4 f = *(const float4*)src;
  unsigned int lo = (unsigned int)f2bf(f.x) | ((unsigned int)f2bf(f.y) << 16);
  unsigned int hi = (unsigned int)f2bf(f.z) | ((unsigned int)f2bf(f.w) << 16);
  *(uint2*)dst = make_uint2(lo, hi);
}

// async global->LDS, 16B per lane. LDS dest is wave-uniform base + lane*16.
__device__ __forceinline__ void g2lds16(const void* g, void* l) {
  unsigned long long gv = (unsigned long long)g;
  unsigned int lv = (unsigned int)(unsigned long long)l;
  __builtin_amdgcn_global_load_lds(
      (const __attribute__((address_space(1))) unsigned int*)gv,
      (__attribute__((address_space(3))) unsigned int*)lv,
      16, 0, 0);
}

// ================= 8-phase projection GEMM (256x256 tile, BK=64, 8 waves 2Mx4N) =================
// LDS tile layout: [256 rows][8 slots of 16B], slot c of row holds source slot c^(row&7)
// (pre-swizzled global source; reads apply the same XOR -> conflict-free ds_read_b128).
// Staged in halves (128 rows = 16KB = 2 global_load_lds per thread).
__device__ __forceinline__ void stage_half512(const unsigned short* src, long long rowBase,
                                              unsigned short* tile, int half, int kOff,
                                              int w, int l) {
#pragma unroll
  for (int i = 0; i < 2; ++i) {
    int t16 = (i * 8 + w) * 64 + l;          // 16B-slot index within half
    int row = t16 >> 3, c = t16 & 7;
    int sc = c ^ (row & 7);
    const unsigned short* g = src + (rowBase + half * 128 + row) * 512ll + kOff + sc * 8;
    g2lds16(g, (char*)tile + half * 16384 + (i * 8 + w) * 1024 + l * 16);
  }
}

// Phase: ds_read A-frags for quadrant Q -> barrier -> setprio(1) -> 16 MFMA -> setprio(0) -> barrier
#define PHASEQ(Q)                                                                           \
  do {                                                                                      \
    bf16x8 afr[2][2];                                                                       \
    _Pragma("unroll") for (int mm = 0; mm < 2; ++mm)                                        \
    _Pragma("unroll") for (int ks = 0; ks < 2; ++ks) {                                      \
      int rowA = wr * 128 + (2 * (Q) + mm) * 16 + r16;                                      \
      int slot = (ks * 4 + g) ^ (rowA & 7);                                                 \
      afr[mm][ks] = *(const bf16x8*)((const char*)Ac + rowA * 128 + slot * 16);             \
    }                                                                                       \
    __builtin_amdgcn_s_barrier();                                                           \
    __builtin_amdgcn_s_setprio(1);                                                          \
    _Pragma("unroll") for (int ks = 0; ks < 2; ++ks)                                        \
    _Pragma("unroll") for (int mm = 0; mm < 2; ++mm)                                        \
    _Pragma("unroll") for (int nf = 0; nf < 4; ++nf)                                        \
      acc[2 * (Q) + mm][nf] = __builtin_amdgcn_mfma_f32_16x16x32_bf16(                      \
          afr[mm][ks], bfr[nf][ks], acc[2 * (Q) + mm][nf], 0, 0, 0);                        \
    __builtin_amdgcn_s_setprio(0);                                                          \
    __builtin_amdgcn_s_barrier();                                                           \
  } while (0)

__global__ __launch_bounds__(512, 2) void gemm_proj8(const unsigned short* A, const unsigned short* Bw,
                                                     const float* biasp, unsigned short* stash,
                                                     float* partial) {
  __shared__ alignas(16) unsigned short Ab[2][16384];   // 2 x 32KB (256x64 bf16)
  __shared__ alignas(16) unsigned short Bb[2][16384];
  __shared__ float rowpart[256][4];
  const int tid = threadIdx.x;
  const int w = tid >> 6, l = tid & 63;
  const int wr = w >> 2, wc = w & 3;        // 2 M-waves x 4 N-waves; wave output 128x64
  const int g = l >> 4, r16 = l & 15;
  // bijective XCD-chunk swizzle: nwg=788, q=98, r=4
  int orig = blockIdx.x;
  int xcd = orig & 7, slot = orig >> 3;
  int wgid = (xcd < 4 ? xcd * 99 : 396 + (xcd - 4) * 98) + slot;
  int mt = wgid & 3, nt = wgid >> 2;        // 4 consecutive wgid share nt -> B-panel L2 reuse

  floatx4 acc[8][4];
  floatx4 zero = {0.f, 0.f, 0.f, 0.f};
#pragma unroll
  for (int i = 0; i < 8; ++i)
#pragma unroll
    for (int j = 0; j < 4; ++j) acc[i][j] = zero;

  const long long mrb = (long long)mt * 256;
  const long long nrb = (long long)nt * 256;

  // prologue: kt0 fully (B then A), kt1 B halves. 12 loads in flight -> wait kt0's 8.
  stage_half512(Bw, nrb, Bb[0], 0, 0, w, l);
  stage_half512(Bw, nrb, Bb[0], 1, 0, w, l);
  stage_half512(A,  mrb, Ab[0], 0, 0, w, l);
  stage_half512(A,  mrb, Ab[0], 1, 0, w, l);
  stage_half512(Bw, nrb, Bb[1], 0, 64, w, l);
  stage_half512(Bw, nrb, Bb[1], 1, 64, w, l);
  asm volatile("s_waitcnt vmcnt(4)" ::: "memory");
  __builtin_amdgcn_s_barrier();

#pragma unroll
  for (int t = 0; t < 8; ++t) {             // K=512, BK=64
    const int c = t & 1;
    const unsigned short* Ac = Ab[c];
    const unsigned short* Bc = Bb[c];
    if (t > 0) {
      // entry invariant: outstanding = [A(t) 4 loads, B(t+1) 4 loads]; need kt t landed.
      if (t < 7) asm volatile("s_waitcnt vmcnt(4)" ::: "memory");
      else       asm volatile("s_waitcnt vmcnt(0)" ::: "memory");
      __builtin_amdgcn_s_barrier();
    }
    // ---- phase 1: stage A-half0(t+1); read all B-frags + A-quad0 ----
    if (t + 1 < 8) stage_half512(A, mrb, Ab[c ^ 1], 0, (t + 1) * 64, w, l);
    bf16x8 bfr[4][2];
#pragma unroll
    for (int nf = 0; nf < 4; ++nf)
#pragma unroll
      for (int ks = 0; ks < 2; ++ks) {
        int rowB = wc * 64 + nf * 16 + r16;
        int slotb = (ks * 4 + g) ^ (rowB & 7);
        bfr[nf][ks] = *(const bf16x8*)((const char*)Bc + rowB * 128 + slotb * 16);
      }
    PHASEQ(0);
    // ---- phase 2: stage A-half1(t+1) ----
    if (t + 1 < 8) stage_half512(A, mrb, Ab[c ^ 1], 1, (t + 1) * 64, w, l);
    PHASEQ(1);
    // ---- phase 3: stage B-half0(t+2) into Bb[c] (B reads of buf c done after phase 1) ----
    if (t + 2 < 8) stage_half512(Bw, nrb, Bb[c], 0, (t + 2) * 64, w, l);
    PHASEQ(2);
    // ---- phase 4: stage B-half1(t+2) ----
    if (t + 2 < 8) stage_half512(Bw, nrb, Bb[c], 1, (t + 2) * 64, w, l);
    PHASEQ(3);
  }

  // epilogue: bias + exp -> bf16 stash + deterministic per-(row,wave) partial sums
  float bcol[4];
#pragma unroll
  for (int nf = 0; nf < 4; ++nf) bcol[nf] = biasp[nt * 256 + wc * 64 + nf * 16 + r16];
#pragma unroll
  for (int mf = 0; mf < 8; ++mf)
#pragma unroll
    for (int qq = 0; qq < 4; ++qq) {
      int rowl = wr * 128 + mf * 16 + g * 4 + qq;
      long long grow = mt * 256 + rowl;
      float s = 0.f;
#pragma unroll
      for (int nf = 0; nf < 4; ++nf) {
        int col = nt * 256 + wc * 64 + nf * 16 + r16;
        float v = __expf(acc[mf][nf][qq] + bcol[nf]);   // pad cols: bias=-1e30 -> v=0
        stash[grow * VP2 + col] = f2bf(v);
        s += v;
      }
      s += __shfl_xor(s, 1); s += __shfl_xor(s, 2);
      s += __shfl_xor(s, 4); s += __shfl_xor(s, 8);
      if (r16 == 0) rowpart[rowl][wc] = s;              // each slot written exactly once
    }
  __syncthreads();
  if (tid < 256) {
    float t4 = (rowpart[tid][0] + rowpart[tid][1]) + (rowpart[tid][2] + rowpart[tid][3]);
    partial[(size_t)(mt * 256 + tid) * NPB2 + nt] = t4;
  }
}

// ================= proven 2-barrier core for GRU gate GEMMs (256x128, 8 waves) =================
__device__ __forceinline__ void compute_step(const unsigned short* Acur, const unsigned short* Bcur,
                                             floatx4 (&acc)[4][4], int wr, int wc, int g, int r16) {
#pragma unroll
  for (int ks = 0; ks < 2; ++ks) {
    bf16x8 a[4], b[4];
#pragma unroll
    for (int i = 0; i < 4; ++i) {
      int rowA = wr * 64 + i * 16 + r16;
      int ca = (ks * 4 + g) ^ (rowA & 7);
      a[i] = *(const bf16x8*)((const char*)Acur + rowA * 128 + ca * 16);
      int rowB = wc * 64 + i * 16 + r16;
      int cb = (ks * 4 + g) ^ (rowB & 7);
      b[i] = *(const bf16x8*)((const char*)Bcur + rowB * 128 + cb * 16);
    }
#pragma unroll
    for (int i = 0; i < 4; ++i)
#pragma unroll
      for (int j = 0; j < 4; ++j)
        acc[i][j] = __builtin_amdgcn_mfma_f32_16x16x32_bf16(a[i], b[j], acc[i][j], 0, 0, 0);
  }
}

__device__ __forceinline__ void gemm_core8(const unsigned short* A, const unsigned short* Bw, int K,
                                           int mt, int nt,
                                           unsigned short* Alds, unsigned short* Blds,
                                           floatx4 (&acc)[4][4]) {
  const int tid = threadIdx.x;
  const int w = tid >> 6, l = tid & 63;
  const int wr = w >> 1, wc = w & 1;
  const int g = l >> 4, r16 = l & 15;
  floatx4 zero = {0.f, 0.f, 0.f, 0.f};
#pragma unroll
  for (int i = 0; i < 4; ++i)
#pragma unroll
    for (int j = 0; j < 4; ++j) acc[i][j] = zero;

  const int nsteps = K >> 6;     // BK = 64
  for (int kt = 0; kt < nsteps; ++kt) {
    __syncthreads();
#pragma unroll
    for (int i = 0; i < 4; ++i) {            // A: 32 chunks of 1KB
      int chunk = w * 4 + i;
      int t16 = chunk * 64 + l;
      int row = t16 >> 3, c = t16 & 7;
      int sc = c ^ (row & 7);
      g2lds16(A + (size_t)(mt * 256 + row) * K + kt * 64 + sc * 8, (char*)Alds + chunk * 1024);
    }
#pragma unroll
    for (int i = 0; i < 2; ++i) {            // B: 16 chunks of 1KB
      int chunk = w * 2 + i;
      int t16 = chunk * 64 + l;
      int row = t16 >> 3, c = t16 & 7;
      int sc = c ^ (row & 7);
      g2lds16(Bw + (size_t)(nt * 128 + row) * K + kt * 64 + sc * 8, (char*)Blds + chunk * 1024);
    }
    __syncthreads();
    compute_step(Alds, Blds, acc, wr, wc, g, r16);
  }
}

struct GemmDesc {
  const unsigned short* A[4];
  const unsigned short* Bw[4];
  const float* bias[4];
  float* C[4];
  int K[4];
};

__global__ __launch_bounds__(512, 4) void gemm_gru_batch(GemmDesc d) {
  __shared__ alignas(16) unsigned short Alds[256 * 64];
  __shared__ alignas(16) unsigned short Blds[128 * 64];
  const int z = blockIdx.z;
  floatx4 acc[4][4];
  gemm_core8(d.A[z], d.Bw[z], d.K[z], blockIdx.y, blockIdx.x, Alds, Blds, acc);
  const float* bias = d.bias[z];
  float* C = d.C[z];
  const int tid = threadIdx.x, w = tid >> 6, l = tid & 63;
  const int wr = w >> 1, wc = w & 1, g = l >> 4, r16 = l & 15;
#pragma unroll
  for (int i = 0; i < 4; ++i)
#pragma unroll
    for (int j = 0; j < 4; ++j) {
      int col = blockIdx.x * 128 + wc * 64 + j * 16 + r16;
      float bc = bias[col];
#pragma unroll
      for (int q = 0; q < 4; ++q) {
        int row = blockIdx.y * 256 + wr * 64 + i * 16 + g * 4 + q;
        C[(size_t)row * NG + col] = acc[i][j][q] + bc;
      }
    }
}

// ================= fallback projection (small ws): f32-B fused core, direct probs ==============
__device__ __forceinline__ void gemm_coreBf32(const unsigned short* A, const float* Bw, int K,
                                              int mt, int nt, int maxrowB,
                                              unsigned short* Alds, unsigned short* Blds,
                                              floatx4 (&acc)[4][4]) {
  const int tid = threadIdx.x;
  const int w = tid >> 6, l = tid & 63;
  const int wr = w >> 1, wc = w & 1;
  const int g = l >> 4, r16 = l & 15;
  floatx4 zero = {0.f, 0.f, 0.f, 0.f};
#pragma unroll
  for (int i = 0; i < 4; ++i)
#pragma unroll
    for (int j = 0; j < 4; ++j) acc[i][j] = zero;
  int brow[2], bsc[2], brg[2];
#pragma unroll
  for (int i = 0; i < 2; ++i) {
    int chunk = w * 2 + i;
    int t16 = chunk * 64 + l;
    brow[i] = t16 >> 3;
    bsc[i] = (t16 & 7) ^ (brow[i] & 7);
    int rg = nt * 128 + brow[i];
    brg[i] = (rg > maxrowB) ? maxrowB : rg;
  }
  const int nsteps = K >> 6;
  for (int kt = 0; kt < nsteps; ++kt) {
    __syncthreads();
    float4 rb[2][2];
#pragma unroll
    for (int i = 0; i < 2; ++i) {
      const float* src = Bw + (size_t)brg[i] * K + kt * 64 + bsc[i] * 8;
      rb[i][0] = *(const float4*)src;
      rb[i][1] = *(const float4*)(src + 4);
    }
#pragma unroll
    for (int i = 0; i < 4; ++i) {
      int chunk = w * 4 + i;
      int t16 = chunk * 64 + l;
      int row = t16 >> 3, c = t16 & 7;
      int sc = c ^ (row & 7);
      g2lds16(A + (size_t)(mt * 256 + row) * K + kt * 64 + sc * 8, (char*)Alds + chunk * 1024);
    }
#pragma unroll
    for (int i = 0; i < 2; ++i) {
      uint4 p;
      p.x = (unsigned int)f2bf(rb[i][0].x) | ((unsigned int)f2bf(rb[i][0].y) << 16);
      p.y = (unsigned int)f2bf(rb[i][0].z) | ((unsigned int)f2bf(rb[i][0].w) << 16);
      p.z = (unsigned int)f2bf(rb[i][1].x) | ((unsigned int)f2bf(rb[i][1].y) << 16);
      p.w = (unsigned int)f2bf(rb[i][1].z) | ((unsigned int)f2bf(rb[i][1].w) << 16);
      *(uint4*)((char*)Blds + (w * 2 + i) * 1024 + l * 16) = p;
    }
    __syncthreads();
    compute_step(Alds, Blds, acc, wr, wc, g, r16);
  }
}

template <int MODE>   // 1: partial sums only. 2: exp*inv -> probs (recompute).
__global__ __launch_bounds__(512, 4) void gemm_proj_fb(const unsigned short* A, const float* Bw,
                                                       const float* biasp, float* probs,
                                                       float* partial, const float* inv) {
  __shared__ alignas(16) unsigned short Alds[256 * 64];
  __shared__ alignas(16) unsigned short Blds[128 * 64];
  __shared__ float rowpart[256];
  const int tid = threadIdx.x;
  if (MODE != 2 && tid < 256) rowpart[tid] = 0.f;
  int orig = blockIdx.x;
  int xcd = orig & 7, slot = orig >> 3;
  int wgid = (xcd < 4 ? xcd * 197 : 788 + (xcd - 4) * 196) + slot;
  int mt = wgid & 3, nt = wgid >> 2;
  floatx4 acc[4][4];
  gemm_coreBf32(A, Bw, 512, mt, nt, Vv - 1, Alds, Blds, acc);
  const int w = tid >> 6, l = tid & 63;
  const int wr = w >> 1, wc = w & 1, g = l >> 4, r16 = l & 15;
  float bcol[4];
#pragma unroll
  for (int j = 0; j < 4; ++j) bcol[j] = biasp[nt * 128 + wc * 64 + j * 16 + r16];
#pragma unroll
  for (int i = 0; i < 4; ++i)
#pragma unroll
    for (int q = 0; q < 4; ++q) {
      int rowl = wr * 64 + i * 16 + g * 4 + q;
      int grow = mt * 256 + rowl;
      float rinv = (MODE == 2) ? inv[grow] : 0.f;
      float s = 0.f;
#pragma unroll
      for (int j = 0; j < 4; ++j) {
        int col = nt * 128 + wc * 64 + j * 16 + r16;
        float v = __expf(acc[i][j][q] + bcol[j]);
        if (MODE == 2) { if (col < Vv) probs[(size_t)grow * Vv + col] = v * rinv; }
        s += v;
      }
      if (MODE != 2) {
        s += __shfl_xor(s, 1); s += __shfl_xor(s, 2);
        s += __shfl_xor(s, 4); s += __shfl_xor(s, 8);
        if (r16 == 0) atomicAdd(&rowpart[rowl], s);
      }
    }
  if (MODE != 2) {
    __syncthreads();
    if (tid < 256) partial[(size_t)(mt * 256 + tid) * NPBF + nt] = rowpart[tid];
  }
}

// ---------------- elementwise GRU gates ---------------------------------------------------------
__global__ __launch_bounds__(256) void gru_gates(const float* Cbuf, const float* hidden,
                                                 float* out_newh, unsigned short* bf_out, int layer) {
  int idx = blockIdx.x * 256 + threadIdx.x;    // 2^20 total
  int j = idx & 511;
  int b = (idx >> 9) & 1023;
  int d = idx >> 19;
  const float* GI = Cbuf + (size_t)d * Bsz * NG;
  const float* GH = Cbuf + (size_t)(2 + d) * Bsz * NG;
  size_t base = (size_t)b * NG + j;
  float ir = GI[base], iz = GI[base + 512], inn = GI[base + 1024];
  float hr = GH[base], hz = GH[base + 512], hn = GH[base + 1024];
  float r = 1.f / (1.f + __expf(-(ir + hr)));
  float z = 1.f / (1.f + __expf(-(iz + hz)));
  float n = tanhf(inn + r * hn);
  size_t hoff = (size_t)(2 * layer + d) * (Bsz * Hs) + (size_t)b * Hs + j;
  float hprev = hidden[hoff];
  float h = (1.f - z) * n + z * hprev;
  out_newh[hoff] = h;
  if (layer == 0) {
    bf_out[(size_t)b * 1024 + d * 512 + j] = f2bf(h);     // inp1 = concat(hf, hb)
  } else if (d == 1) {
    bf_out[(size_t)b * 512 + j] = f2bf(h);                // hb1 feeds projection
  }
}

// ---------------- conversions (vectorized x4; Wproj padded to VP2 rows) -------------------------
__global__ void convert_all(const float* Wih0, const float* Whh0, const float* Wih1, const float* Whh1,
                            const float* hidden, const float* Wproj, const float* bproj,
                            unsigned short* wih0b, unsigned short* whh0b, unsigned short* wih1b,
                            unsigned short* whh1b, unsigned short* hbf, unsigned short* wprojb,
                            float* bprojp) {
  long long idx = ((long long)blockIdx.x * 256 + threadIdx.x) * 4;
  if (idx < 1572864) { cvt4(Wih0 + idx, wih0b + idx); return; }
  idx -= 1572864;
  if (idx < 1572864) { cvt4(Whh0 + idx, whh0b + idx); return; }
  idx -= 1572864;
  if (idx < 3145728) { cvt4(Wih1 + idx, wih1b + idx); return; }
  idx -= 3145728;
  if (idx < 1572864) { cvt4(Whh1 + idx, whh1b + idx); return; }
  idx -= 1572864;
  if (idx < 2097152) { cvt4(hidden + idx, hbf + idx); return; }
  idx -= 2097152;
  if (idx < 25821184) {          // Wproj padded [50432][512]
    long long row = idx >> 9, col = idx & 511;
    if (row < Vv) cvt4(Wproj + row * 512 + col, wprojb + idx);
    else *(uint2*)(wprojb + idx) = make_uint2(0u, 0u);
    return;
  }
  idx -= 25821184;
  if (idx < VP2) {
    float4 v;
    v.x = (idx + 0 < Vv) ? bproj[idx + 0] : -1e30f;
    v.y = (idx + 1 < Vv) ? bproj[idx + 1] : -1e30f;
    v.z = (idx + 2 < Vv) ? bproj[idx + 2] : -1e30f;
    v.w = (idx + 3 < Vv) ? bproj[idx + 3] : -1e30f;
    *(float4*)(bprojp + idx) = v;
  }
}

__global__ void gather_embed(const int* x, const float* embed, unsigned short* xe) {
  int b = blockIdx.x, t = threadIdx.x;
  int tok = x[b];
  float2 v = *(const float2*)(embed + (size_t)tok * 512 + t * 2);
  unsigned int o = ((unsigned int)f2bf(v.y) << 16) | f2bf(v.x);
  *(unsigned int*)((unsigned short*)xe + (size_t)b * 512 + t * 2) = o;
}

// ---------------- softmax normalization --------------------------------------------------------
__global__ void rowsum_inv(const float* partial, float* inv, int npb) {
  int row = blockIdx.x, tid = threadIdx.x;   // 128 threads
  float s = 0.f;
  for (int c = tid; c < npb; c += 128) s += partial[(size_t)row * npb + c];
  __shared__ float tmp[128];
  tmp[tid] = s;
  __syncthreads();
  for (int off = 64; off > 0; off >>= 1) {
    if (tid < off) tmp[tid] += tmp[tid + off];
    __syncthreads();
  }
  if (tid == 0) inv[row] = 1.0f / tmp[0];
}

// Flat-index normalize+expand: thread f owns probs[4f..4f+4) -> aligned float4 store, no tail.
__global__ __launch_bounds__(256) void scale_expand(const unsigned short* stash, const float* inv,
                                                    float* probs) {
  const unsigned int nquad = 12865792u;        // (1024*50257)/4 exactly
  const unsigned int step = gridDim.x * 256u;
  for (unsigned int f = blockIdx.x * 256u + threadIdx.x; f < nquad; f += step) {
    unsigned int e0 = f * 4u;
    unsigned int row = e0 / (unsigned int)Vv;  // magic-multiply division
    int col = (int)(e0 - row * (unsigned int)Vv);
    float4 o;
    if (col + 4 <= Vv) {
      float s = inv[row];
      const unsigned short* sp = stash + (size_t)row * VP2 + col;
      if ((col & 1) == 0) {
        unsigned int u0 = *(const unsigned int*)sp;
        unsigned int u1 = *(const unsigned int*)(sp + 2);
        o.x = bf2f((unsigned short)u0) * s;
        o.y = bf2f((unsigned short)(u0 >> 16)) * s;
        o.z = bf2f((unsigned short)u1) * s;
        o.w = bf2f((unsigned short)(u1 >> 16)) * s;
      } else {
        o.x = bf2f(sp[0]) * s; o.y = bf2f(sp[1]) * s;
        o.z = bf2f(sp[2]) * s; o.w = bf2f(sp[3]) * s;
      }
    } else {
      float vals[4];
#pragma unroll
      for (int k = 0; k < 4; ++k) {
        unsigned int e = e0 + k;
        unsigned int rk = e / (unsigned int)Vv;
        int ck = (int)(e - rk * (unsigned int)Vv);
        vals[k] = bf2f(stash[(size_t)rk * VP2 + ck]) * inv[rk];
      }
      o.x = vals[0]; o.y = vals[1]; o.z = vals[2]; o.w = vals[3];
    }
    *(float4*)(probs + e0) = o;
  }
}

// ---------------- host-side launch -------------------------------------------------------------
extern "C" void kernel_launch(void* const* d_in, const int* in_sizes, int n_in,
                              void* d_out, int out_size, void* d_ws, size_t ws_size,
                              hipStream_t stream) {
  const int*   x      = (const int*)d_in[0];
  const float* hidden = (const float*)d_in[1];
  const float* embed  = (const float*)d_in[2];
  const float* Wih0   = (const float*)d_in[3];
  const float* Whh0   = (const float*)d_in[4];
  const float* bih0   = (const float*)d_in[5];
  const float* bhh0   = (const float*)d_in[6];
  const float* Wih1   = (const float*)d_in[7];
  const float* Whh1   = (const float*)d_in[8];
  const float* bih1   = (const float*)d_in[9];
  const float* bhh1   = (const float*)d_in[10];
  const float* Wproj  = (const float*)d_in[11];
  const float* bproj  = (const float*)d_in[12];
  float* out = (float*)d_out;

  char* ws = (char*)d_ws;
  unsigned short* wih0b  = (unsigned short*)(ws);              //  3,145,728 B
  unsigned short* whh0b  = (unsigned short*)(ws + 3145728);    //  3,145,728 B
  unsigned short* wih1b  = (unsigned short*)(ws + 6291456);    //  6,291,456 B
  unsigned short* whh1b  = (unsigned short*)(ws + 12582912);   //  3,145,728 B
  unsigned short* hbf    = (unsigned short*)(ws + 15728640);   //  4,194,304 B
  float*          bprojp = (float*)(ws + 19922944);            //    201,728 B (VP2)
  unsigned short* xe     = (unsigned short*)(ws + 20124672);   //  1,048,576 B
  unsigned short* inp1   = (unsigned short*)(ws + 21173248);   //  2,097,152 B
  unsigned short* hb1    = (unsigned short*)(ws + 23270400);   //  1,048,576 B
  unsigned short* wprojb = (unsigned short*)(ws + 24318976);   // 51,642,368 B (VP2 x 512 bf16)
  float*          partial= (float*)(ws + 75961344);            //  1,609,728 B (max of both paths)
  float*          inv    = (float*)(ws + 77571072);            //      4,096 B
  float*          Cbuf   = (float*)(ws + 77575168);            // 25,165,824 B
  unsigned short* stash  = (unsigned short*)(ws + 77575168);   // 103,284,736 B (aliases Cbuf:
                                                               //  disjoint lifetimes)
  const size_t NEED_STASH = 77575168ull + (size_t)Bsz * VP2 * 2ull;   // ~180.9 MB (proven ws>=205.6)

  float* out_newh = out + 51463168ll;   // 1024*50257

  convert_all<<<34994, 256, 0, stream>>>(Wih0, Whh0, Wih1, Whh1, hidden, Wproj, bproj,
                                         wih0b, whh0b, wih1b, whh1b, hbf, wprojb, bprojp);
  gather_embed<<<1024, 256, 0, stream>>>(x, embed, xe);

  // layer 0
  GemmDesc d0;
  d0.A[0] = xe;  d0.A[1] = xe;
  d0.A[2] = hbf; d0.A[3] = hbf + 524288;
  d0.Bw[0] = wih0b; d0.Bw[1] = wih0b + 786432;
  d0.Bw[2] = whh0b; d0.Bw[3] = whh0b + 786432;
  d0.bias[0] = bih0; d0.bias[1] = bih0 + 1536;
  d0.bias[2] = bhh0; d0.bias[3] = bhh0 + 1536;
  d0.C[0] = Cbuf;             d0.C[1] = Cbuf + 1572864;
  d0.C[2] = Cbuf + 2*1572864; d0.C[3] = Cbuf + 3*1572864;
  d0.K[0] = d0.K[1] = d0.K[2] = d0.K[3] = 512;
  gemm_gru_batch<<<dim3(12, 4, 4), 512, 0, stream>>>(d0);
  gru_gates<<<4096, 256, 0, stream>>>(Cbuf, hidden, out_newh, inp1, 0);

  // layer 1
  GemmDesc d1;
  d1.A[0] = inp1; d1.A[1] = inp1;
  d1.A[2] = hbf + 2*524288; d1.A[3] = hbf + 3*524288;
  d1.Bw[0] = wih1b; d1.Bw[1] = wih1b + 1572864;
  d1.Bw[2] = whh1b; d1.Bw[3] = whh1b + 786432;
  d1.bias[0] = bih1; d1.bias[1] = bih1 + 1536;
  d1.bias[2] = bhh1; d1.bias[3] = bhh1 + 1536;
  d1.C[0] = Cbuf;             d1.C[1] = Cbuf + 1572864;
  d1.C[2] = Cbuf + 2*1572864; d1.C[3] = Cbuf + 3*1572864;
  d1.K[0] = d1.K[1] = 1024; d1.K[2] = d1.K[3] = 512;
  gemm_gru_batch<<<dim3(12, 4, 4), 512, 0, stream>>>(d1);
  gru_gates<<<4096, 256, 0, stream>>>(Cbuf, hidden, out_newh, hb1, 1);

  // projection + softmax
  if (ws_size >= NEED_STASH) {
    gemm_proj8<<<788, 512, 0, stream>>>(hb1, wprojb, bprojp, stash, partial);
    rowsum_inv<<<1024, 128, 0, stream>>>(partial, inv, NPB2);
    scale_expand<<<8192, 256, 0, stream>>>(stash, inv, out);
  } else {
    gemm_proj_fb<1><<<1572, 512, 0, stream>>>(hb1, Wproj, bprojp, out, partial, inv);
    rowsum_inv<<<1024, 128, 0, stream>>>(partial, inv, NPBF);
    gemm_proj_fb<2><<<1572, 512, 0, stream>>>(hb1, Wproj, bprojp, out, partial, inv);
  }
}